// Round 9
// baseline (257.772 us; speedup 1.0000x reference)
//
#include <hip/hip_runtime.h>

typedef __bf16 bf16x8 __attribute__((ext_vector_type(8)));
typedef float f32x4 __attribute__((ext_vector_type(4)));
typedef unsigned short u16;

#define D_MODEL 1024
#define SEQ     2048
#define BATCH   4
#define NH      16
#define DH      64

// Q is stored prescaled by 1/sqrt(Dh) * log2(e); attn uses exp2 directly.
#define QSCALE 0.18033688011f

// both-sides bank swizzle for the epilogue bounce buffer: injects byte bits
// [9:7] (per-lane-distinct, non-bank) into bank bits [6:4]. Keeps [3:0].
#define SWZ(b) ((b) ^ ((((b) >> 8) & 3) << 5) ^ ((((b) >> 7) & 1) << 4))

static __device__ __forceinline__ u16 f2bf(float f) {
    union { float f; unsigned u; } v; v.f = f;
    unsigned r = v.u + 0x7FFF + ((v.u >> 16) & 1);  // RNE
    return (u16)(r >> 16);
}
static __device__ __forceinline__ void storeC(u16* C, size_t off, float v) { C[off] = f2bf(v); }
static __device__ __forceinline__ void storeC(float* C, size_t off, float v) { C[off] = v; }

// async global->LDS, 16 B per lane; lds must be wave-uniform base
static __device__ __forceinline__ void async_ld16(u16* lds, const u16* g) {
    __builtin_amdgcn_global_load_lds(
        (const __attribute__((address_space(1))) unsigned int*)g,
        (__attribute__((address_space(3))) unsigned int*)lds, 16, 0, 0);
}

// ---------------------------------------------------------------------------
// Merged prepass (single launch):
//   blocks [0,4096)          : fp32 -> bf16 convert of x (8 elems/thread)
//   blocks [4096,7168)       : transpose qkv_w [1024][3072] -> [3072][1024]
//   blocks [7168,8192)       : transpose out_w [1024][1024] -> [1024][1024]
// ---------------------------------------------------------------------------
__global__ __launch_bounds__(256) void prepass(
    const float* __restrict__ x,     u16* __restrict__ xb,
    const float* __restrict__ qkv_w, u16* __restrict__ Wqkv_t,
    const float* __restrict__ out_w, u16* __restrict__ Wout_t) {
    __shared__ float tile[32][33];
    int bid = blockIdx.x, tid = threadIdx.x;

    if (bid < 4096) {                       // cvt_bf16 part
        size_t i = ((size_t)bid * 256 + tid) * 8;
        float4 a = *(const float4*)(x + i);
        float4 b = *(const float4*)(x + i + 4);
        u16 t[8] = {f2bf(a.x), f2bf(a.y), f2bf(a.z), f2bf(a.w),
                    f2bf(b.x), f2bf(b.y), f2bf(b.z), f2bf(b.w)};
        *(uint4*)(xb + i) = *(uint4*)t;
        return;
    }

    const float* in; u16* out; int n0, k0, N;
    if (bid < 7168) {                       // qkv_w transpose
        int bb = bid - 4096;                // [0,3072)
        n0 = (bb % 96) * 32; k0 = (bb / 96) * 32;
        in = qkv_w; out = Wqkv_t; N = 3 * D_MODEL;
    } else {                                // out_w transpose
        int bb = bid - 7168;                // [0,1024)
        n0 = (bb & 31) * 32; k0 = (bb >> 5) * 32;
        in = out_w; out = Wout_t; N = D_MODEL;
    }
    int tx = tid & 31, ty = tid >> 5;
    for (int i = ty; i < 32; i += 8)
        tile[i][tx] = in[(size_t)(k0 + i) * N + n0 + tx];
    __syncthreads();
    for (int i = ty; i < 32; i += 8)
        out[(size_t)(n0 + i) * D_MODEL + k0 + tx] = f2bf(tile[tx][i]);
}

// ---------------------------------------------------------------------------
// Generic GEMM: C[M,N] = A @ Bt^T + bias.  128x128 tile, 4 waves.
// 2-phase counted schedule (verified R2): double-buffered LDS; prefetch next
// tile before computing current; one __syncthreads per K-iteration.
// ---------------------------------------------------------------------------
template <typename CT>
__global__ __launch_bounds__(256) void gemm_bt(
    const u16* __restrict__ A, int lda,
    const u16* __restrict__ Bt, int ldb,
    const float* __restrict__ bias,
    CT* __restrict__ C, int ldc, int K) {
    __shared__ u16 As[2][128 * 64];
    __shared__ u16 Bs[2][128 * 64];
    int m0 = blockIdx.x * 128, n0 = blockIdx.y * 128;
    int tid = threadIdx.x;
    int w = tid >> 6, lane = tid & 63, l15 = lane & 15, g = lane >> 4;
    int wm = (w & 1) * 64, wn = (w >> 1) * 64;
    int srow = w * 8 + (lane >> 3);
    int sk8  = lane & 7;

    auto stage = [&](int buf, int kt) {
        #pragma unroll
        for (int p = 0; p < 4; ++p) {
            int row = p * 32 + srow;
            int k8 = sk8 ^ (row & 7);
            async_ld16(&As[buf][p * 2048 + w * 512],
                       A + (size_t)(m0 + row) * lda + kt + k8 * 8);
            async_ld16(&Bs[buf][p * 2048 + w * 512],
                       Bt + (size_t)(n0 + row) * ldb + kt + k8 * 8);
        }
    };

    f32x4 acc[4][4] = {};

    stage(0, 0);
    __syncthreads();
    for (int kt = 0; kt < K; kt += 64) {
        int cur = (kt >> 6) & 1;
        if (kt + 64 < K) stage(cur ^ 1, kt + 64);   // prefetch next tile
        #pragma unroll
        for (int kk = 0; kk < 2; ++kk) {
            bf16x8 af[4], bf_[4];
            int s8 = ((kk << 2) | g) ^ (l15 & 7);
            #pragma unroll
            for (int i = 0; i < 4; ++i) {
                af[i]  = *(const bf16x8*)&As[cur][(wm + i * 16 + l15) * 64 + s8 * 8];
                bf_[i] = *(const bf16x8*)&Bs[cur][(wn + i * 16 + l15) * 64 + s8 * 8];
            }
            #pragma unroll
            for (int i = 0; i < 4; ++i)
                #pragma unroll
                for (int j = 0; j < 4; ++j)
                    acc[i][j] = __builtin_amdgcn_mfma_f32_16x16x32_bf16(
                        af[i], bf_[j], acc[i][j], 0, 0, 0);
        }
        __syncthreads();   // drains vmcnt: next buffer staged for everyone
    }
    #pragma unroll
    for (int j = 0; j < 4; ++j) {
        int n = n0 + wn + j * 16 + l15;
        float bv = bias[n];
        #pragma unroll
        for (int i = 0; i < 4; ++i) {
            int mbase = m0 + wm + i * 16 + g * 4;
            #pragma unroll
            for (int r = 0; r < 4; ++r)
                storeC(C, (size_t)(mbase + r) * ldc + n, acc[i][j][r] + bv);
        }
    }
}

// ---------------------------------------------------------------------------
// QKV GEMM (128x128, 2-phase counted schedule) with fused epilogue:
//   Q columns  -> Qd [M][1024] dense bf16, PRESCALED by QSCALE (direct store)
//   K columns  -> Kd [bh][s][64] DENSE bf16 (direct store, 32B runs — attn
//                 reads its B-fragment straight from dense rows)
//   V columns  -> pkV fragment-packed via SWIZZLED LDS-BOUNCE (V genuinely
//                 needs the transpose: attn consumes 8 consecutive keys of
//                 one dim). Values bitwise-identical either path.
// region is uniform per block (n0 128-aligned, regions 1024-aligned).
// ---------------------------------------------------------------------------
__global__ __launch_bounds__(256) void gemm_qkv(
    const u16* __restrict__ A,            // xb [M][1024]
    const u16* __restrict__ Bt,           // Wqkv_t [3072][1024]
    const float* __restrict__ bias,       // [3072]
    u16* __restrict__ Qd, u16* __restrict__ Kd, u16* __restrict__ pkV) {
    __shared__ u16 As[2][128 * 64];
    __shared__ u16 Bs[2][128 * 64];
    const int K = D_MODEL;
    int m0 = blockIdx.x * 128, n0 = blockIdx.y * 128;
    int tid = threadIdx.x;
    int w = tid >> 6, lane = tid & 63, l15 = lane & 15, g = lane >> 4;
    int wm = (w & 1) * 64, wn = (w >> 1) * 64;
    int srow = w * 8 + (lane >> 3);
    int sk8  = lane & 7;

    auto stage = [&](int buf, int kt) {
        #pragma unroll
        for (int p = 0; p < 4; ++p) {
            int row = p * 32 + srow;
            int k8 = sk8 ^ (row & 7);
            async_ld16(&As[buf][p * 2048 + w * 512],
                       A + (size_t)(m0 + row) * K + kt + k8 * 8);
            async_ld16(&Bs[buf][p * 2048 + w * 512],
                       Bt + (size_t)(n0 + row) * K + kt + k8 * 8);
        }
    };

    f32x4 acc[4][4] = {};

    stage(0, 0);
    __syncthreads();
    for (int kt = 0; kt < K; kt += 64) {
        int cur = (kt >> 6) & 1;
        if (kt + 64 < K) stage(cur ^ 1, kt + 64);   // prefetch next tile
        #pragma unroll
        for (int kk = 0; kk < 2; ++kk) {
            bf16x8 af[4], bf_[4];
            int s8 = ((kk << 2) | g) ^ (l15 & 7);
            #pragma unroll
            for (int i = 0; i < 4; ++i) {
                af[i]  = *(const bf16x8*)&As[cur][(wm + i * 16 + l15) * 64 + s8 * 8];
                bf_[i] = *(const bf16x8*)&Bs[cur][(wn + i * 16 + l15) * 64 + s8 * 8];
            }
            #pragma unroll
            for (int i = 0; i < 4; ++i)
                #pragma unroll
                for (int j = 0; j < 4; ++j)
                    acc[i][j] = __builtin_amdgcn_mfma_f32_16x16x32_bf16(
                        af[i], bf_[j], acc[i][j], 0, 0, 0);
        }
        __syncthreads();   // drains vmcnt: next buffer staged for everyone
        // after the LAST iteration this barrier also makes As/Bs reusable
    }

    int region = n0 >> 10;                 // block-uniform
    if (region == 0) {
        // ---- dense Q store, prescaled (32B-sector runs) ----
        #pragma unroll
        for (int j = 0; j < 4; ++j) {
            int n = n0 + wn + j * 16 + l15;
            float bv = bias[n];
            int hd = n & 1023;
            #pragma unroll
            for (int i = 0; i < 4; ++i) {
                #pragma unroll
                for (int r = 0; r < 4; ++r) {
                    int m = m0 + wm + i * 16 + g * 4 + r;
                    Qd[(size_t)m * 1024 + hd] =
                        f2bf((acc[i][j][r] + bv) * QSCALE);
                }
            }
        }
        return;
    }
    if (region == 1) {
        // ---- dense K store: Kd[bh][s][64], 32B-sector runs ----
        #pragma unroll
        for (int j = 0; j < 4; ++j) {
            int n = n0 + wn + j * 16 + l15;
            float bv = bias[n];
            int hd = n & 1023;
            int h = hd >> 6, d = hd & 63;
            #pragma unroll
            for (int i = 0; i < 4; ++i) {
                #pragma unroll
                for (int r = 0; r < 4; ++r) {
                    int m = m0 + wm + i * 16 + g * 4 + r;
                    int b = m >> 11, s = m & 2047;
                    Kd[((size_t)(b * 16 + h) * 2048 + s) * 64 + d] =
                        f2bf(acc[i][j][r] + bv);
                }
            }
        }
        return;
    }

    // ---- V: swizzled LDS-bounce into packed layout, coalesced copy ----
    char* lds = (char*)As;                 // 32 KB scratch (main loop done)
    int h0 = (n0 & 1023) >> 6;             // first head col-group of tile
    int t0 = (m0 & 2047) >> 6;             // first t-chunk of tile
    int bb = m0 >> 11;                     // batch (m0 never crosses)

    // V: r-values consecutive -> pack 4 into one 8B write (SWZ keeps
    // bits [3:0], so 8B alignment is preserved)
    #pragma unroll
    for (int j = 0; j < 4; ++j) {
        int dn = wn + j * 16 + l15;
        float bv = bias[n0 + dn];
        int hp = dn >> 6, d = dn & 63;
        int nb = d >> 4, lv = d & 15;
        #pragma unroll
        for (int i = 0; i < 4; ++i) {
            int mmb = wm + i * 16 + g * 4;          // r-base row
            int tp = mmb >> 6, kapb = mmb & 63;
            int kk = kapb >> 5, gv = (kapb >> 3) & 3, jvb = kapb & 7;
            union { u16 q[4]; unsigned long long ll; } p4;
            #pragma unroll
            for (int r = 0; r < 4; ++r)
                p4.q[r] = f2bf(acc[i][j][r] + bv);
            int o = (((nb * 2 + kk) * 64 + gv * 16 + lv) * 8 + jvb) * 2;
            *(unsigned long long*)(lds + (hp * 2 + tp) * 8192 + SWZ(o)) =
                p4.ll;
        }
    }
    __syncthreads();
    #pragma unroll
    for (int c = 0; c < 4; ++c) {
        int hp = c >> 1, tp = c & 1;
        u16* dst = pkV + ((size_t)((bb * 16 + h0 + hp) * 32) + t0 + tp) * 4096;
        int o0 = tid * 32, o1 = tid * 32 + 16;
        uint4 v0 = *(uint4*)(lds + c * 8192 + SWZ(o0));
        uint4 v1 = *(uint4*)(lds + c * 8192 + SWZ(o1));
        *(uint4*)&dst[tid * 16]     = v0;
        *(uint4*)&dst[tid * 16 + 8] = v1;
    }
}

// ---------------------------------------------------------------------------
// Flash attention, causal, no-max softmax — TLP-maximized 2-wave blocks:
// one q-tile per block, each wave owns 32 q-rows over the FULL K range.
// No split-K, no merge phase, ZERO barriers, per-wave Pt in LDS (9.2 KB).
// grid = (B*NH, 32) with qt = 31 - blockIdx.y (largest tiles dispatch first
// -> LPT load balancing of the variable causal work).
// K now reads DIRECTLY from dense Kd rows (B-fragment = 16 rows x 64B
// contiguous chunks per b128 load — semi-coalesced, L2-resident, TLP-hidden).
// V streams from packed pkV (coalesced b128). Q prescaled -> exp2 direct.
// Diag-split: mask ops only on the final (diagonal) tile.
// ---------------------------------------------------------------------------
__global__ __launch_bounds__(128) void attn_flash(
    u16* __restrict__ Qd, const u16* __restrict__ Kd,
    const u16* __restrict__ pkV) {
    __shared__ __align__(16) u16 Pt[2][32][72];     // per-wave [32 q][72]

    int bh = blockIdx.x, b = bh >> 4, h = bh & 15;
    int tid = threadIdx.x;
    int w = tid >> 6, lane = tid & 63, l15 = lane & 15, g = lane >> 4;

    const u16* Kb = Kd + (size_t)bh * 2048 * 64;    // dense [s][64]
    const u16* Vb = pkV + (size_t)bh * 32 * 4096;   // packed
    u16* Qbase = Qd + (size_t)b * SEQ * 1024 + h * DH;

    int qt = 31 - (int)blockIdx.y;      // big tiles first (LPT)
    int q0 = qt * 64;

    // Q fragments (already prescaled by QSCALE in gemm_qkv)
    bf16x8 qfrag[2][2];
    #pragma unroll
    for (int st = 0; st < 2; ++st) {
        const u16* qp = Qbase + (size_t)(q0 + w * 32 + st * 16 + l15) * 1024 + g * 8;
        qfrag[st][0] = *(const bf16x8*)qp;
        qfrag[st][1] = *(const bf16x8*)(qp + 32);
    }

    f32x4 o[2][4] = {};
    float lsum[2][4] = {};

    auto ktile = [&](int t, bool diag) {
        const u16* kt = Kb + (size_t)t * 64 * 64;   // dense rows
        const u16* vt = Vb + t * 4096;
        bf16x8 kf[4][2], vf[4][2];
        #pragma unroll
        for (int nb = 0; nb < 4; ++nb) {
            #pragma unroll
            for (int kk = 0; kk < 2; ++kk) {
                kf[nb][kk] = *(const bf16x8*)(kt + (nb * 16 + l15) * 64 + kk * 32 + g * 8);
                vf[nb][kk] = *(const bf16x8*)(vt + ((nb * 2 + kk) * 64 + lane) * 8);
            }
        }
        int k0 = t * 64;

        #pragma unroll
        for (int st = 0; st < 2; ++st) {
            f32x4 s[4] = {};
            #pragma unroll
            for (int nb = 0; nb < 4; ++nb)
                #pragma unroll
                for (int kk = 0; kk < 2; ++kk)
                    s[nb] = __builtin_amdgcn_mfma_f32_16x16x32_bf16(
                        qfrag[st][kk], kf[nb][kk], s[nb], 0, 0, 0);

            #pragma unroll
            for (int r = 0; r < 4; ++r) {
                int qg = q0 + w * 32 + st * 16 + g * 4 + r;
                #pragma unroll
                for (int nb = 0; nb < 4; ++nb) {
                    float p = __builtin_amdgcn_exp2f(s[nb][r]);
                    if (diag && (k0 + nb * 16 + l15) > qg) p = 0.f;
                    lsum[st][r] += p;
                    Pt[w][st * 16 + g * 4 + r][nb * 16 + l15] =
                        (u16)(__float_as_uint(p) >> 16);
                }
            }

            #pragma unroll
            for (int kk = 0; kk < 2; ++kk) {
                bf16x8 aP = *(const bf16x8*)&Pt[w][st * 16 + l15][kk * 32 + g * 8];
                #pragma unroll
                for (int nb = 0; nb < 4; ++nb)
                    o[st][nb] = __builtin_amdgcn_mfma_f32_16x16x32_bf16(
                        aP, vf[nb][kk], o[st][nb], 0, 0, 0);
            }
        }
    };

    // mask-free main loop; diagonal tile handled once, with mask
    for (int t = 0; t < qt; ++t) ktile(t, false);
    ktile(qt, true);

    // per-wave row-sum butterfly (16 cols across 16 lanes)
    #pragma unroll
    for (int msk = 1; msk < 16; msk <<= 1)
        #pragma unroll
        for (int st = 0; st < 2; ++st)
            #pragma unroll
            for (int r = 0; r < 4; ++r)
                lsum[st][r] += __shfl_xor(lsum[st][r], msk, 64);

    // direct normalize + store (wave owns its rows fully; no merge)
    #pragma unroll
    for (int st = 0; st < 2; ++st)
        #pragma unroll
        for (int r = 0; r < 4; ++r) {
            int qrow = w * 32 + st * 16 + g * 4 + r;
            float inv = 1.f / lsum[st][r];
            u16* op = Qbase + (size_t)(q0 + qrow) * 1024;
            #pragma unroll
            for (int nb = 0; nb < 4; ++nb)
                op[nb * 16 + l15] = f2bf(o[st][nb][r] * inv);
        }
}

// ---------------------------------------------------------------------------
extern "C" void kernel_launch(void* const* d_in, const int* in_sizes, int n_in,
                              void* d_out, int out_size, void* d_ws, size_t ws_size,
                              hipStream_t stream) {
    const float* x     = (const float*)d_in[0];
    const float* qkv_w = (const float*)d_in[1];
    const float* qkv_b = (const float*)d_in[2];
    const float* out_w = (const float*)d_in[3];
    const float* out_b = (const float*)d_in[4];
    float* out = (float*)d_out;

    const int M = BATCH * SEQ;                             // 8192
    u16* Qd     = (u16*)d_ws;                              // [M][1024]      16.8 MB
    u16* Kd     = Qd  + (size_t)M * D_MODEL;               // [64][2048][64] 16.8 MB
    u16* pkV    = Kd  + (size_t)64 * 2048 * 64;            //                16.8 MB
    u16* xb     = pkV + (size_t)64 * 32 * 4096;            // [M][1024]      16.8 MB
    u16* Wqkv_t = xb  + (size_t)M * D_MODEL;               // [3072][1024]    6.3 MB
    u16* Wout_t = Wqkv_t + (size_t)3 * D_MODEL * D_MODEL;  // [1024][1024]    2.1 MB

    // merged prepass: cvt + both weight transposes in one launch
    prepass<<<dim3(8192), 256, 0, stream>>>(x, xb, qkv_w, Wqkv_t, out_w, Wout_t);

    // QKV projection: Q/K dense stores, V packed via swizzled bounce
    gemm_qkv<<<dim3(M / 128, 3 * D_MODEL / 128), 256, 0, stream>>>(
        xb, Wqkv_t, qkv_b, Qd, Kd, pkV);

    // causal flash attention, 2-wave blocks, one q-tile each, LPT order
    attn_flash<<<dim3(BATCH * NH, SEQ / 64), 128, 0, stream>>>(Qd, Kd, pkV);

    // output projection
    gemm_bt<float><<<dim3(M / 128, D_MODEL / 128), 256, 0, stream>>>(
        Qd, D_MODEL, Wout_t, D_MODEL, out_b, out, D_MODEL, D_MODEL);
}

// Round 10
// 242.987 us; speedup vs baseline: 1.0608x; 1.0608x over previous
//
#include <hip/hip_runtime.h>

typedef __bf16 bf16x8 __attribute__((ext_vector_type(8)));
typedef float f32x4 __attribute__((ext_vector_type(4)));
typedef unsigned short u16;

#define D_MODEL 1024
#define SEQ     2048
#define BATCH   4
#define NH      16
#define DH      64

// Q is stored prescaled by 1/sqrt(Dh) * log2(e); attn uses exp2 directly.
#define QSCALE 0.18033688011f

// both-sides bank swizzle for the epilogue bounce buffer: injects byte bits
// [9:7] (per-lane-distinct, non-bank) into bank bits [6:4]. Keeps [3:0].
#define SWZ(b) ((b) ^ ((((b) >> 8) & 3) << 5) ^ ((((b) >> 7) & 1) << 4))

static __device__ __forceinline__ u16 f2bf(float f) {
    union { float f; unsigned u; } v; v.f = f;
    unsigned r = v.u + 0x7FFF + ((v.u >> 16) & 1);  // RNE
    return (u16)(r >> 16);
}
static __device__ __forceinline__ void storeC(u16* C, size_t off, float v) { C[off] = f2bf(v); }
static __device__ __forceinline__ void storeC(float* C, size_t off, float v) { C[off] = v; }

// async global->LDS, 16 B per lane; lds must be wave-uniform base
static __device__ __forceinline__ void async_ld16(u16* lds, const u16* g) {
    __builtin_amdgcn_global_load_lds(
        (const __attribute__((address_space(1))) unsigned int*)g,
        (__attribute__((address_space(3))) unsigned int*)lds, 16, 0, 0);
}

// ---------------------------------------------------------------------------
// Merged prepass (single launch):
//   blocks [0,4096)          : fp32 -> bf16 convert of x (8 elems/thread)
//   blocks [4096,7168)       : transpose qkv_w [1024][3072] -> [3072][1024]
//   blocks [7168,8192)       : transpose out_w [1024][1024] -> [1024][1024]
// ---------------------------------------------------------------------------
__global__ __launch_bounds__(256) void prepass(
    const float* __restrict__ x,     u16* __restrict__ xb,
    const float* __restrict__ qkv_w, u16* __restrict__ Wqkv_t,
    const float* __restrict__ out_w, u16* __restrict__ Wout_t) {
    __shared__ float tile[32][33];
    int bid = blockIdx.x, tid = threadIdx.x;

    if (bid < 4096) {                       // cvt_bf16 part
        size_t i = ((size_t)bid * 256 + tid) * 8;
        float4 a = *(const float4*)(x + i);
        float4 b = *(const float4*)(x + i + 4);
        u16 t[8] = {f2bf(a.x), f2bf(a.y), f2bf(a.z), f2bf(a.w),
                    f2bf(b.x), f2bf(b.y), f2bf(b.z), f2bf(b.w)};
        *(uint4*)(xb + i) = *(uint4*)t;
        return;
    }

    const float* in; u16* out; int n0, k0, N;
    if (bid < 7168) {                       // qkv_w transpose
        int bb = bid - 4096;                // [0,3072)
        n0 = (bb % 96) * 32; k0 = (bb / 96) * 32;
        in = qkv_w; out = Wqkv_t; N = 3 * D_MODEL;
    } else {                                // out_w transpose
        int bb = bid - 7168;                // [0,1024)
        n0 = (bb & 31) * 32; k0 = (bb >> 5) * 32;
        in = out_w; out = Wout_t; N = D_MODEL;
    }
    int tx = tid & 31, ty = tid >> 5;
    for (int i = ty; i < 32; i += 8)
        tile[i][tx] = in[(size_t)(k0 + i) * N + n0 + tx];
    __syncthreads();
    for (int i = ty; i < 32; i += 8)
        out[(size_t)(n0 + i) * D_MODEL + k0 + tx] = f2bf(tile[tx][i]);
}

// ---------------------------------------------------------------------------
// Generic GEMM: C[M,N] = A @ Bt^T + bias.  128x128 tile, 4 waves.
// 2-phase counted schedule (verified R2): double-buffered LDS; prefetch next
// tile before computing current; one __syncthreads per K-iteration.
// ---------------------------------------------------------------------------
template <typename CT>
__global__ __launch_bounds__(256) void gemm_bt(
    const u16* __restrict__ A, int lda,
    const u16* __restrict__ Bt, int ldb,
    const float* __restrict__ bias,
    CT* __restrict__ C, int ldc, int K) {
    __shared__ u16 As[2][128 * 64];
    __shared__ u16 Bs[2][128 * 64];
    int m0 = blockIdx.x * 128, n0 = blockIdx.y * 128;
    int tid = threadIdx.x;
    int w = tid >> 6, lane = tid & 63, l15 = lane & 15, g = lane >> 4;
    int wm = (w & 1) * 64, wn = (w >> 1) * 64;
    int srow = w * 8 + (lane >> 3);
    int sk8  = lane & 7;

    auto stage = [&](int buf, int kt) {
        #pragma unroll
        for (int p = 0; p < 4; ++p) {
            int row = p * 32 + srow;
            int k8 = sk8 ^ (row & 7);
            async_ld16(&As[buf][p * 2048 + w * 512],
                       A + (size_t)(m0 + row) * lda + kt + k8 * 8);
            async_ld16(&Bs[buf][p * 2048 + w * 512],
                       Bt + (size_t)(n0 + row) * ldb + kt + k8 * 8);
        }
    };

    f32x4 acc[4][4] = {};

    stage(0, 0);
    __syncthreads();
    for (int kt = 0; kt < K; kt += 64) {
        int cur = (kt >> 6) & 1;
        if (kt + 64 < K) stage(cur ^ 1, kt + 64);   // prefetch next tile
        #pragma unroll
        for (int kk = 0; kk < 2; ++kk) {
            bf16x8 af[4], bf_[4];
            int s8 = ((kk << 2) | g) ^ (l15 & 7);
            #pragma unroll
            for (int i = 0; i < 4; ++i) {
                af[i]  = *(const bf16x8*)&As[cur][(wm + i * 16 + l15) * 64 + s8 * 8];
                bf_[i] = *(const bf16x8*)&Bs[cur][(wn + i * 16 + l15) * 64 + s8 * 8];
            }
            #pragma unroll
            for (int i = 0; i < 4; ++i)
                #pragma unroll
                for (int j = 0; j < 4; ++j)
                    acc[i][j] = __builtin_amdgcn_mfma_f32_16x16x32_bf16(
                        af[i], bf_[j], acc[i][j], 0, 0, 0);
        }
        __syncthreads();   // drains vmcnt: next buffer staged for everyone
    }
    #pragma unroll
    for (int j = 0; j < 4; ++j) {
        int n = n0 + wn + j * 16 + l15;
        float bv = bias[n];
        #pragma unroll
        for (int i = 0; i < 4; ++i) {
            int mbase = m0 + wm + i * 16 + g * 4;
            #pragma unroll
            for (int r = 0; r < 4; ++r)
                storeC(C, (size_t)(mbase + r) * ldc + n, acc[i][j][r] + bv);
        }
    }
}

// ---------------------------------------------------------------------------
// QKV GEMM — BK=32 double-buffered (LDS 32 KB total -> 5 blocks/CU, 20
// waves/CU: barrier/drain stalls now interleave across 5 independent blocks;
// R8's attn proved this stall class yields to residency).
// Staging: 2 passes x 64 rows x 4 granules of 8 elems; swizzle
// k8 = sg ^ (row&3), fragment read at g ^ (l15&3). MFMA sequence per acc is
// the identical instruction order as BK=64 -> bitwise-identical output.
// Epilogue (identical to R8):
//   Q -> Qd dense, PRESCALED; K -> pkK packed via SWIZZLED LDS-BOUNCE;
//   V -> pkV packed via SWIZZLED LDS-BOUNCE. smem (32 KB) doubles as the
//   bounce scratch (4 chunks x 8 KB).
// ---------------------------------------------------------------------------
__global__ __launch_bounds__(256) void gemm_qkv(
    const u16* __restrict__ A,            // xb [M][1024]
    const u16* __restrict__ Bt,           // Wqkv_t [3072][1024]
    const float* __restrict__ bias,       // [3072]
    u16* __restrict__ Qd, u16* __restrict__ pkK, u16* __restrict__ pkV) {
    __shared__ u16 smem[16384];           // 32 KB: As[2][4096] | Bs[2][4096]
    u16* As = smem;
    u16* Bs = smem + 8192;
    const int K = D_MODEL;
    int m0 = blockIdx.x * 128, n0 = blockIdx.y * 128;
    int tid = threadIdx.x;
    int w = tid >> 6, lane = tid & 63, l15 = lane & 15, g = lane >> 4;
    int wm = (w & 1) * 64, wn = (w >> 1) * 64;
    int srow = w * 16 + (lane >> 2);      // row within 64-row pass
    int sg4  = lane & 3;

    auto stage = [&](int buf, int kt) {
        #pragma unroll
        for (int p = 0; p < 2; ++p) {
            int row = p * 64 + srow;
            int k8 = sg4 ^ (row & 3);
            async_ld16(&As[buf * 4096 + p * 2048 + w * 512],
                       A + (size_t)(m0 + row) * K + kt + k8 * 8);
            async_ld16(&Bs[buf * 4096 + p * 2048 + w * 512],
                       Bt + (size_t)(n0 + row) * K + kt + k8 * 8);
        }
    };

    f32x4 acc[4][4] = {};

    stage(0, 0);
    __syncthreads();
    for (int kt = 0; kt < K; kt += 32) {
        int cur = (kt >> 5) & 1;
        if (kt + 32 < K) stage(cur ^ 1, kt + 32);   // prefetch next tile
        bf16x8 af[4], bf_[4];
        int s4 = g ^ (l15 & 3);
        #pragma unroll
        for (int i = 0; i < 4; ++i) {
            af[i]  = *(const bf16x8*)&As[cur * 4096 + (wm + i * 16 + l15) * 32 + s4 * 8];
            bf_[i] = *(const bf16x8*)&Bs[cur * 4096 + (wn + i * 16 + l15) * 32 + s4 * 8];
        }
        #pragma unroll
        for (int i = 0; i < 4; ++i)
            #pragma unroll
            for (int j = 0; j < 4; ++j)
                acc[i][j] = __builtin_amdgcn_mfma_f32_16x16x32_bf16(
                    af[i], bf_[j], acc[i][j], 0, 0, 0);
        __syncthreads();   // drains vmcnt: next buffer staged for everyone
        // after the LAST iteration this barrier also makes smem reusable
    }

    int region = n0 >> 10;                 // block-uniform
    if (region == 0) {
        // ---- dense Q store, prescaled (32B-sector runs) ----
        #pragma unroll
        for (int j = 0; j < 4; ++j) {
            int n = n0 + wn + j * 16 + l15;
            float bv = bias[n];
            int hd = n & 1023;
            #pragma unroll
            for (int i = 0; i < 4; ++i) {
                #pragma unroll
                for (int r = 0; r < 4; ++r) {
                    int m = m0 + wm + i * 16 + g * 4 + r;
                    Qd[(size_t)m * 1024 + hd] =
                        f2bf((acc[i][j][r] + bv) * QSCALE);
                }
            }
        }
        return;
    }

    // ---- K/V: swizzled LDS-bounce into packed layout, coalesced copy ----
    char* lds = (char*)smem;               // 32 KB scratch (main loop done)
    int h0 = (n0 & 1023) >> 6;             // first head col-group of tile
    int t0 = (m0 & 2047) >> 6;             // first t-chunk of tile
    int bb = m0 >> 11;                     // batch (m0 never crosses)

    if (region == 1) {
        // K: lk from row, kk/gk/jk from col; b16 writes at SWZ'd offsets
        #pragma unroll
        for (int j = 0; j < 4; ++j) {
            int dn = wn + j * 16 + l15;    // col within tile [0,128)
            float bv = bias[n0 + dn];
            int hp = dn >> 6, d = dn & 63;
            int kk = d >> 5, gk = (d >> 3) & 3, jk = d & 7;
            #pragma unroll
            for (int i = 0; i < 4; ++i) {
                #pragma unroll
                for (int r = 0; r < 4; ++r) {
                    int mm = wm + i * 16 + g * 4 + r;   // row within tile
                    int tp = mm >> 6, kap = mm & 63;
                    int nb = kap >> 4, lk = kap & 15;
                    int o = (((nb * 2 + kk) * 64 + gk * 16 + lk) * 8 + jk) * 2;
                    *(u16*)(lds + (hp * 2 + tp) * 8192 + SWZ(o)) =
                        f2bf(acc[i][j][r] + bv);
                }
            }
        }
    } else {
        // V: r-values consecutive -> pack 4 into one 8B write (SWZ keeps
        // bits [3:0], so 8B alignment is preserved)
        #pragma unroll
        for (int j = 0; j < 4; ++j) {
            int dn = wn + j * 16 + l15;
            float bv = bias[n0 + dn];
            int hp = dn >> 6, d = dn & 63;
            int nb = d >> 4, lv = d & 15;
            #pragma unroll
            for (int i = 0; i < 4; ++i) {
                int mmb = wm + i * 16 + g * 4;          // r-base row
                int tp = mmb >> 6, kapb = mmb & 63;
                int kk = kapb >> 5, gv = (kapb >> 3) & 3, jvb = kapb & 7;
                union { u16 q[4]; unsigned long long ll; } p4;
                #pragma unroll
                for (int r = 0; r < 4; ++r)
                    p4.q[r] = f2bf(acc[i][j][r] + bv);
                int o = (((nb * 2 + kk) * 64 + gv * 16 + lv) * 8 + jvb) * 2;
                *(unsigned long long*)(lds + (hp * 2 + tp) * 8192 + SWZ(o)) =
                    p4.ll;
            }
        }
    }
    __syncthreads();
    u16* pk = (region == 1) ? pkK : pkV;
    #pragma unroll
    for (int c = 0; c < 4; ++c) {
        int hp = c >> 1, tp = c & 1;
        u16* dst = pk + ((size_t)((bb * 16 + h0 + hp) * 32) + t0 + tp) * 4096;
        int o0 = tid * 32, o1 = tid * 32 + 16;
        uint4 v0 = *(uint4*)(lds + c * 8192 + SWZ(o0));
        uint4 v1 = *(uint4*)(lds + c * 8192 + SWZ(o1));
        *(uint4*)&dst[tid * 16]     = v0;
        *(uint4*)&dst[tid * 16 + 8] = v1;
    }
}

// ---------------------------------------------------------------------------
// Flash attention, causal, no-max softmax — TLP-maximized 2-wave blocks (R8):
// one q-tile per block, each wave owns 32 q-rows over the FULL K range.
// No split-K, no merge phase, ZERO barriers, per-wave Pt in LDS (9.2 KB).
// grid = (B*NH, 32) with qt = 31 - blockIdx.y (largest tiles dispatch first
// -> LPT load balancing of the variable causal work).
// K/V fragments stream from PACKED buffers (coalesced b128 loads; latency
// hidden by high block residency — R7/R9 showed dur tracks occupancy and
// request count, so packed layouts stay).
// Q comes prescaled by QSCALE -> p = exp2(s) directly.
// Diag-split: mask ops only on the final (diagonal) tile.
// ---------------------------------------------------------------------------
__global__ __launch_bounds__(128) void attn_flash(
    u16* __restrict__ Qd, const u16* __restrict__ pkK,
    const u16* __restrict__ pkV) {
    __shared__ __align__(16) u16 Pt[2][32][72];     // per-wave [32 q][72]

    int bh = blockIdx.x, b = bh >> 4, h = bh & 15;
    int tid = threadIdx.x;
    int w = tid >> 6, lane = tid & 63, l15 = lane & 15, g = lane >> 4;

    const u16* Kb = pkK + (size_t)bh * 32 * 4096;
    const u16* Vb = pkV + (size_t)bh * 32 * 4096;
    u16* Qbase = Qd + (size_t)b * SEQ * 1024 + h * DH;

    int qt = 31 - (int)blockIdx.y;      // big tiles first (LPT)
    int q0 = qt * 64;

    // Q fragments (already prescaled by QSCALE in gemm_qkv)
    bf16x8 qfrag[2][2];
    #pragma unroll
    for (int st = 0; st < 2; ++st) {
        const u16* qp = Qbase + (size_t)(q0 + w * 32 + st * 16 + l15) * 1024 + g * 8;
        qfrag[st][0] = *(const bf16x8*)qp;
        qfrag[st][1] = *(const bf16x8*)(qp + 32);
    }

    f32x4 o[2][4] = {};
    float lsum[2][4] = {};

    auto ktile = [&](int t, bool diag) {
        const u16* kt = Kb + t * 4096;
        const u16* vt = Vb + t * 4096;
        bf16x8 kf[4][2], vf[4][2];
        #pragma unroll
        for (int nb = 0; nb < 4; ++nb) {
            #pragma unroll
            for (int kk = 0; kk < 2; ++kk) {
                kf[nb][kk] = *(const bf16x8*)(kt + ((nb * 2 + kk) * 64 + lane) * 8);
                vf[nb][kk] = *(const bf16x8*)(vt + ((nb * 2 + kk) * 64 + lane) * 8);
            }
        }
        int k0 = t * 64;

        #pragma unroll
        for (int st = 0; st < 2; ++st) {
            f32x4 s[4] = {};
            #pragma unroll
            for (int nb = 0; nb < 4; ++nb)
                #pragma unroll
                for (int kk = 0; kk < 2; ++kk)
                    s[nb] = __builtin_amdgcn_mfma_f32_16x16x32_bf16(
                        qfrag[st][kk], kf[nb][kk], s[nb], 0, 0, 0);

            #pragma unroll
            for (int r = 0; r < 4; ++r) {
                int qg = q0 + w * 32 + st * 16 + g * 4 + r;
                #pragma unroll
                for (int nb = 0; nb < 4; ++nb) {
                    float p = __builtin_amdgcn_exp2f(s[nb][r]);
                    if (diag && (k0 + nb * 16 + l15) > qg) p = 0.f;
                    lsum[st][r] += p;
                    Pt[w][st * 16 + g * 4 + r][nb * 16 + l15] =
                        (u16)(__float_as_uint(p) >> 16);
                }
            }

            #pragma unroll
            for (int kk = 0; kk < 2; ++kk) {
                bf16x8 aP = *(const bf16x8*)&Pt[w][st * 16 + l15][kk * 32 + g * 8];
                #pragma unroll
                for (int nb = 0; nb < 4; ++nb)
                    o[st][nb] = __builtin_amdgcn_mfma_f32_16x16x32_bf16(
                        aP, vf[nb][kk], o[st][nb], 0, 0, 0);
            }
        }
    };

    // mask-free main loop; diagonal tile handled once, with mask
    for (int t = 0; t < qt; ++t) ktile(t, false);
    ktile(qt, true);

    // per-wave row-sum butterfly (16 cols across 16 lanes)
    #pragma unroll
    for (int msk = 1; msk < 16; msk <<= 1)
        #pragma unroll
        for (int st = 0; st < 2; ++st)
            #pragma unroll
            for (int r = 0; r < 4; ++r)
                lsum[st][r] += __shfl_xor(lsum[st][r], msk, 64);

    // direct normalize + store (wave owns its rows fully; no merge)
    #pragma unroll
    for (int st = 0; st < 2; ++st)
        #pragma unroll
        for (int r = 0; r < 4; ++r) {
            int qrow = w * 32 + st * 16 + g * 4 + r;
            float inv = 1.f / lsum[st][r];
            u16* op = Qbase + (size_t)(q0 + qrow) * 1024;
            #pragma unroll
            for (int nb = 0; nb < 4; ++nb)
                op[nb * 16 + l15] = f2bf(o[st][nb][r] * inv);
        }
}

// ---------------------------------------------------------------------------
extern "C" void kernel_launch(void* const* d_in, const int* in_sizes, int n_in,
                              void* d_out, int out_size, void* d_ws, size_t ws_size,
                              hipStream_t stream) {
    const float* x     = (const float*)d_in[0];
    const float* qkv_w = (const float*)d_in[1];
    const float* qkv_b = (const float*)d_in[2];
    const float* out_w = (const float*)d_in[3];
    const float* out_b = (const float*)d_in[4];
    float* out = (float*)d_out;

    const int M = BATCH * SEQ;                             // 8192
    u16* Qd     = (u16*)d_ws;                              // [M][1024]      16.8 MB
    u16* pkK    = Qd  + (size_t)M * D_MODEL;               // [64][32][4096] 16.8 MB
    u16* pkV    = pkK + (size_t)64 * 32 * 4096;            //                16.8 MB
    u16* xb     = pkV + (size_t)64 * 32 * 4096;            // [M][1024]      16.8 MB
    u16* Wqkv_t = xb  + (size_t)M * D_MODEL;               // [3072][1024]    6.3 MB
    u16* Wout_t = Wqkv_t + (size_t)3 * D_MODEL * D_MODEL;  // [1024][1024]    2.1 MB

    // merged prepass: cvt + both weight transposes in one launch
    prepass<<<dim3(8192), 256, 0, stream>>>(x, xb, qkv_w, Wqkv_t, out_w, Wout_t);

    // QKV projection with fused scatter into Qd / packed K / packed V
    gemm_qkv<<<dim3(M / 128, 3 * D_MODEL / 128), 256, 0, stream>>>(
        xb, Wqkv_t, qkv_b, Qd, pkK, pkV);

    // causal flash attention, 2-wave blocks, one q-tile each, LPT order
    attn_flash<<<dim3(BATCH * NH, SEQ / 64), 128, 0, stream>>>(Qd, pkK, pkV);

    // output projection
    gemm_bt<float><<<dim3(M / 128, D_MODEL / 128), 256, 0, stream>>>(
        Qd, D_MODEL, Wout_t, D_MODEL, out_b, out, D_MODEL, D_MODEL);
}

// Round 11
// 238.418 us; speedup vs baseline: 1.0812x; 1.0192x over previous
//
#include <hip/hip_runtime.h>

typedef __bf16 bf16x8 __attribute__((ext_vector_type(8)));
typedef float f32x4 __attribute__((ext_vector_type(4)));
typedef unsigned short u16;

#define D_MODEL 1024
#define SEQ     2048
#define BATCH   4
#define NH      16
#define DH      64

// Q is stored prescaled by 1/sqrt(Dh) * log2(e); attn uses exp2 directly.
#define QSCALE 0.18033688011f

// both-sides bank swizzle for the epilogue bounce buffer: injects byte bits
// [9:7] (per-lane-distinct, non-bank) into bank bits [6:4]. Keeps [3:0].
#define SWZ(b) ((b) ^ ((((b) >> 8) & 3) << 5) ^ ((((b) >> 7) & 1) << 4))

static __device__ __forceinline__ u16 f2bf(float f) {
    union { float f; unsigned u; } v; v.f = f;
    unsigned r = v.u + 0x7FFF + ((v.u >> 16) & 1);  // RNE
    return (u16)(r >> 16);
}
static __device__ __forceinline__ void storeC(u16* C, size_t off, float v) { C[off] = f2bf(v); }
static __device__ __forceinline__ void storeC(float* C, size_t off, float v) { C[off] = v; }

// async global->LDS, 16 B per lane; lds must be wave-uniform base
static __device__ __forceinline__ void async_ld16(u16* lds, const u16* g) {
    __builtin_amdgcn_global_load_lds(
        (const __attribute__((address_space(1))) unsigned int*)g,
        (__attribute__((address_space(3))) unsigned int*)lds, 16, 0, 0);
}

// ---------------------------------------------------------------------------
// Merged prepass (single launch):
//   blocks [0,4096)          : fp32 -> bf16 convert of x (8 elems/thread)
//   blocks [4096,7168)       : transpose qkv_w [1024][3072] -> [3072][1024]
//   blocks [7168,8192)       : transpose out_w [1024][1024] -> [1024][1024]
// ---------------------------------------------------------------------------
__global__ __launch_bounds__(256) void prepass(
    const float* __restrict__ x,     u16* __restrict__ xb,
    const float* __restrict__ qkv_w, u16* __restrict__ Wqkv_t,
    const float* __restrict__ out_w, u16* __restrict__ Wout_t) {
    __shared__ float tile[32][33];
    int bid = blockIdx.x, tid = threadIdx.x;

    if (bid < 4096) {                       // cvt_bf16 part
        size_t i = ((size_t)bid * 256 + tid) * 8;
        float4 a = *(const float4*)(x + i);
        float4 b = *(const float4*)(x + i + 4);
        u16 t[8] = {f2bf(a.x), f2bf(a.y), f2bf(a.z), f2bf(a.w),
                    f2bf(b.x), f2bf(b.y), f2bf(b.z), f2bf(b.w)};
        *(uint4*)(xb + i) = *(uint4*)t;
        return;
    }

    const float* in; u16* out; int n0, k0, N;
    if (bid < 7168) {                       // qkv_w transpose
        int bb = bid - 4096;                // [0,3072)
        n0 = (bb % 96) * 32; k0 = (bb / 96) * 32;
        in = qkv_w; out = Wqkv_t; N = 3 * D_MODEL;
    } else {                                // out_w transpose
        int bb = bid - 7168;                // [0,1024)
        n0 = (bb & 31) * 32; k0 = (bb >> 5) * 32;
        in = out_w; out = Wout_t; N = D_MODEL;
    }
    int tx = tid & 31, ty = tid >> 5;
    for (int i = ty; i < 32; i += 8)
        tile[i][tx] = in[(size_t)(k0 + i) * N + n0 + tx];
    __syncthreads();
    for (int i = ty; i < 32; i += 8)
        out[(size_t)(n0 + i) * D_MODEL + k0 + tx] = f2bf(tile[tx][i]);
}

// ---------------------------------------------------------------------------
// Generic GEMM: C[M,N] = A @ Bt^T + bias.  128x128 tile, 4 waves.
// 2-phase counted schedule (verified R2): double-buffered LDS; prefetch next
// tile before computing current; one __syncthreads per K-iteration.
// ---------------------------------------------------------------------------
template <typename CT>
__global__ __launch_bounds__(256) void gemm_bt(
    const u16* __restrict__ A, int lda,
    const u16* __restrict__ Bt, int ldb,
    const float* __restrict__ bias,
    CT* __restrict__ C, int ldc, int K) {
    __shared__ u16 As[2][128 * 64];
    __shared__ u16 Bs[2][128 * 64];
    int m0 = blockIdx.x * 128, n0 = blockIdx.y * 128;
    int tid = threadIdx.x;
    int w = tid >> 6, lane = tid & 63, l15 = lane & 15, g = lane >> 4;
    int wm = (w & 1) * 64, wn = (w >> 1) * 64;
    int srow = w * 8 + (lane >> 3);
    int sk8  = lane & 7;

    auto stage = [&](int buf, int kt) {
        #pragma unroll
        for (int p = 0; p < 4; ++p) {
            int row = p * 32 + srow;
            int k8 = sk8 ^ (row & 7);
            async_ld16(&As[buf][p * 2048 + w * 512],
                       A + (size_t)(m0 + row) * lda + kt + k8 * 8);
            async_ld16(&Bs[buf][p * 2048 + w * 512],
                       Bt + (size_t)(n0 + row) * ldb + kt + k8 * 8);
        }
    };

    f32x4 acc[4][4] = {};

    stage(0, 0);
    __syncthreads();
    for (int kt = 0; kt < K; kt += 64) {
        int cur = (kt >> 6) & 1;
        if (kt + 64 < K) stage(cur ^ 1, kt + 64);   // prefetch next tile
        #pragma unroll
        for (int kk = 0; kk < 2; ++kk) {
            bf16x8 af[4], bf_[4];
            int s8 = ((kk << 2) | g) ^ (l15 & 7);
            #pragma unroll
            for (int i = 0; i < 4; ++i) {
                af[i]  = *(const bf16x8*)&As[cur][(wm + i * 16 + l15) * 64 + s8 * 8];
                bf_[i] = *(const bf16x8*)&Bs[cur][(wn + i * 16 + l15) * 64 + s8 * 8];
            }
            #pragma unroll
            for (int i = 0; i < 4; ++i)
                #pragma unroll
                for (int j = 0; j < 4; ++j)
                    acc[i][j] = __builtin_amdgcn_mfma_f32_16x16x32_bf16(
                        af[i], bf_[j], acc[i][j], 0, 0, 0);
        }
        __syncthreads();   // drains vmcnt: next buffer staged for everyone
    }
    #pragma unroll
    for (int j = 0; j < 4; ++j) {
        int n = n0 + wn + j * 16 + l15;
        float bv = bias[n];
        #pragma unroll
        for (int i = 0; i < 4; ++i) {
            int mbase = m0 + wm + i * 16 + g * 4;
            #pragma unroll
            for (int r = 0; r < 4; ++r)
                storeC(C, (size_t)(mbase + r) * ldc + n, acc[i][j][r] + bv);
        }
    }
}

// ---------------------------------------------------------------------------
// QKV GEMM — BK=32 double-buffered (LDS 32 KB -> 5 blocks/CU, 20 waves/CU).
// Bank-conflict-FIXED fragment swizzle (R10 post-mortem): with 64 B rows the
// bank group is (row&1)*16 + s4*4, and row&1 aliases l15&1 — so the XOR
// source must be row bits [2:1] (which don't reach the bank field), not
// row bits [1:0]. stage: k8 = sg4 ^ ((row>>1)&3); read: s4 = g ^ ((l15>>1)&3)
// -> per quarter-wave l15&7 spans all 8 bank groups = 2 lanes/group = free.
// MFMA sequence per acc identical to BK=64 -> bitwise-identical output.
// Epilogue (identical to R8): Q dense PRESCALED; K/V packed via SWIZZLED
// LDS-BOUNCE; smem (32 KB) doubles as bounce scratch (4 x 8 KB chunks).
// ---------------------------------------------------------------------------
__global__ __launch_bounds__(256) void gemm_qkv(
    const u16* __restrict__ A,            // xb [M][1024]
    const u16* __restrict__ Bt,           // Wqkv_t [3072][1024]
    const float* __restrict__ bias,       // [3072]
    u16* __restrict__ Qd, u16* __restrict__ pkK, u16* __restrict__ pkV) {
    __shared__ u16 smem[16384];           // 32 KB: As[2][4096] | Bs[2][4096]
    u16* As = smem;
    u16* Bs = smem + 8192;
    const int K = D_MODEL;
    int m0 = blockIdx.x * 128, n0 = blockIdx.y * 128;
    int tid = threadIdx.x;
    int w = tid >> 6, lane = tid & 63, l15 = lane & 15, g = lane >> 4;
    int wm = (w & 1) * 64, wn = (w >> 1) * 64;
    int srow = w * 16 + (lane >> 2);      // row within 64-row pass
    int sg4  = lane & 3;

    auto stage = [&](int buf, int kt) {
        #pragma unroll
        for (int p = 0; p < 2; ++p) {
            int row = p * 64 + srow;
            int k8 = sg4 ^ ((row >> 1) & 3);
            async_ld16(&As[buf * 4096 + p * 2048 + w * 512],
                       A + (size_t)(m0 + row) * K + kt + k8 * 8);
            async_ld16(&Bs[buf * 4096 + p * 2048 + w * 512],
                       Bt + (size_t)(n0 + row) * K + kt + k8 * 8);
        }
    };

    f32x4 acc[4][4] = {};

    stage(0, 0);
    __syncthreads();
    for (int kt = 0; kt < K; kt += 32) {
        int cur = (kt >> 5) & 1;
        if (kt + 32 < K) stage(cur ^ 1, kt + 32);   // prefetch next tile
        bf16x8 af[4], bf_[4];
        int s4 = g ^ ((l15 >> 1) & 3);
        #pragma unroll
        for (int i = 0; i < 4; ++i) {
            af[i]  = *(const bf16x8*)&As[cur * 4096 + (wm + i * 16 + l15) * 32 + s4 * 8];
            bf_[i] = *(const bf16x8*)&Bs[cur * 4096 + (wn + i * 16 + l15) * 32 + s4 * 8];
        }
        #pragma unroll
        for (int i = 0; i < 4; ++i)
            #pragma unroll
            for (int j = 0; j < 4; ++j)
                acc[i][j] = __builtin_amdgcn_mfma_f32_16x16x32_bf16(
                    af[i], bf_[j], acc[i][j], 0, 0, 0);
        __syncthreads();   // drains vmcnt: next buffer staged for everyone
        // after the LAST iteration this barrier also makes smem reusable
    }

    int region = n0 >> 10;                 // block-uniform
    if (region == 0) {
        // ---- dense Q store, prescaled (32B-sector runs) ----
        #pragma unroll
        for (int j = 0; j < 4; ++j) {
            int n = n0 + wn + j * 16 + l15;
            float bv = bias[n];
            int hd = n & 1023;
            #pragma unroll
            for (int i = 0; i < 4; ++i) {
                #pragma unroll
                for (int r = 0; r < 4; ++r) {
                    int m = m0 + wm + i * 16 + g * 4 + r;
                    Qd[(size_t)m * 1024 + hd] =
                        f2bf((acc[i][j][r] + bv) * QSCALE);
                }
            }
        }
        return;
    }

    // ---- K/V: swizzled LDS-bounce into packed layout, coalesced copy ----
    char* lds = (char*)smem;               // 32 KB scratch (main loop done)
    int h0 = (n0 & 1023) >> 6;             // first head col-group of tile
    int t0 = (m0 & 2047) >> 6;             // first t-chunk of tile
    int bb = m0 >> 11;                     // batch (m0 never crosses)

    if (region == 1) {
        // K: lk from row, kk/gk/jk from col; b16 writes at SWZ'd offsets
        #pragma unroll
        for (int j = 0; j < 4; ++j) {
            int dn = wn + j * 16 + l15;    // col within tile [0,128)
            float bv = bias[n0 + dn];
            int hp = dn >> 6, d = dn & 63;
            int kk = d >> 5, gk = (d >> 3) & 3, jk = d & 7;
            #pragma unroll
            for (int i = 0; i < 4; ++i) {
                #pragma unroll
                for (int r = 0; r < 4; ++r) {
                    int mm = wm + i * 16 + g * 4 + r;   // row within tile
                    int tp = mm >> 6, kap = mm & 63;
                    int nb = kap >> 4, lk = kap & 15;
                    int o = (((nb * 2 + kk) * 64 + gk * 16 + lk) * 8 + jk) * 2;
                    *(u16*)(lds + (hp * 2 + tp) * 8192 + SWZ(o)) =
                        f2bf(acc[i][j][r] + bv);
                }
            }
        }
    } else {
        // V: r-values consecutive -> pack 4 into one 8B write (SWZ keeps
        // bits [3:0], so 8B alignment is preserved)
        #pragma unroll
        for (int j = 0; j < 4; ++j) {
            int dn = wn + j * 16 + l15;
            float bv = bias[n0 + dn];
            int hp = dn >> 6, d = dn & 63;
            int nb = d >> 4, lv = d & 15;
            #pragma unroll
            for (int i = 0; i < 4; ++i) {
                int mmb = wm + i * 16 + g * 4;          // r-base row
                int tp = mmb >> 6, kapb = mmb & 63;
                int kk = kapb >> 5, gv = (kapb >> 3) & 3, jvb = kapb & 7;
                union { u16 q[4]; unsigned long long ll; } p4;
                #pragma unroll
                for (int r = 0; r < 4; ++r)
                    p4.q[r] = f2bf(acc[i][j][r] + bv);
                int o = (((nb * 2 + kk) * 64 + gv * 16 + lv) * 8 + jvb) * 2;
                *(unsigned long long*)(lds + (hp * 2 + tp) * 8192 + SWZ(o)) =
                    p4.ll;
            }
        }
    }
    __syncthreads();
    u16* pk = (region == 1) ? pkK : pkV;
    #pragma unroll
    for (int c = 0; c < 4; ++c) {
        int hp = c >> 1, tp = c & 1;
        u16* dst = pk + ((size_t)((bb * 16 + h0 + hp) * 32) + t0 + tp) * 4096;
        int o0 = tid * 32, o1 = tid * 32 + 16;
        uint4 v0 = *(uint4*)(lds + c * 8192 + SWZ(o0));
        uint4 v1 = *(uint4*)(lds + c * 8192 + SWZ(o1));
        *(uint4*)&dst[tid * 16]     = v0;
        *(uint4*)&dst[tid * 16 + 8] = v1;
    }
}

// ---------------------------------------------------------------------------
// Flash attention, causal, no-max softmax — TLP-maximized 2-wave blocks (R8):
// one q-tile per block, each wave owns 32 q-rows over the FULL K range.
// No split-K, no merge phase, ZERO barriers, per-wave Pt in LDS (9.2 KB).
// grid = (B*NH, 32) with qt = 31 - blockIdx.y (largest tiles dispatch first
// -> LPT load balancing of the variable causal work).
// K/V fragments stream from PACKED buffers (coalesced b128 loads; latency
// hidden by high block residency — R7/R9 showed dur tracks occupancy and
// request count, so packed layouts stay).
// Q comes prescaled by QSCALE -> p = exp2(s) directly.
// Diag-split: mask ops only on the final (diagonal) tile.
// ---------------------------------------------------------------------------
__global__ __launch_bounds__(128) void attn_flash(
    u16* __restrict__ Qd, const u16* __restrict__ pkK,
    const u16* __restrict__ pkV) {
    __shared__ __align__(16) u16 Pt[2][32][72];     // per-wave [32 q][72]

    int bh = blockIdx.x, b = bh >> 4, h = bh & 15;
    int tid = threadIdx.x;
    int w = tid >> 6, lane = tid & 63, l15 = lane & 15, g = lane >> 4;

    const u16* Kb = pkK + (size_t)bh * 32 * 4096;
    const u16* Vb = pkV + (size_t)bh * 32 * 4096;
    u16* Qbase = Qd + (size_t)b * SEQ * 1024 + h * DH;

    int qt = 31 - (int)blockIdx.y;      // big tiles first (LPT)
    int q0 = qt * 64;

    // Q fragments (already prescaled by QSCALE in gemm_qkv)
    bf16x8 qfrag[2][2];
    #pragma unroll
    for (int st = 0; st < 2; ++st) {
        const u16* qp = Qbase + (size_t)(q0 + w * 32 + st * 16 + l15) * 1024 + g * 8;
        qfrag[st][0] = *(const bf16x8*)qp;
        qfrag[st][1] = *(const bf16x8*)(qp + 32);
    }

    f32x4 o[2][4] = {};
    float lsum[2][4] = {};

    auto ktile = [&](int t, bool diag) {
        const u16* kt = Kb + t * 4096;
        const u16* vt = Vb + t * 4096;
        bf16x8 kf[4][2], vf[4][2];
        #pragma unroll
        for (int nb = 0; nb < 4; ++nb) {
            #pragma unroll
            for (int kk = 0; kk < 2; ++kk) {
                kf[nb][kk] = *(const bf16x8*)(kt + ((nb * 2 + kk) * 64 + lane) * 8);
                vf[nb][kk] = *(const bf16x8*)(vt + ((nb * 2 + kk) * 64 + lane) * 8);
            }
        }
        int k0 = t * 64;

        #pragma unroll
        for (int st = 0; st < 2; ++st) {
            f32x4 s[4] = {};
            #pragma unroll
            for (int nb = 0; nb < 4; ++nb)
                #pragma unroll
                for (int kk = 0; kk < 2; ++kk)
                    s[nb] = __builtin_amdgcn_mfma_f32_16x16x32_bf16(
                        qfrag[st][kk], kf[nb][kk], s[nb], 0, 0, 0);

            #pragma unroll
            for (int r = 0; r < 4; ++r) {
                int qg = q0 + w * 32 + st * 16 + g * 4 + r;
                #pragma unroll
                for (int nb = 0; nb < 4; ++nb) {
                    float p = __builtin_amdgcn_exp2f(s[nb][r]);
                    if (diag && (k0 + nb * 16 + l15) > qg) p = 0.f;
                    lsum[st][r] += p;
                    Pt[w][st * 16 + g * 4 + r][nb * 16 + l15] =
                        (u16)(__float_as_uint(p) >> 16);
                }
            }

            #pragma unroll
            for (int kk = 0; kk < 2; ++kk) {
                bf16x8 aP = *(const bf16x8*)&Pt[w][st * 16 + l15][kk * 32 + g * 8];
                #pragma unroll
                for (int nb = 0; nb < 4; ++nb)
                    o[st][nb] = __builtin_amdgcn_mfma_f32_16x16x32_bf16(
                        aP, vf[nb][kk], o[st][nb], 0, 0, 0);
            }
        }
    };

    // mask-free main loop; diagonal tile handled once, with mask
    for (int t = 0; t < qt; ++t) ktile(t, false);
    ktile(qt, true);

    // per-wave row-sum butterfly (16 cols across 16 lanes)
    #pragma unroll
    for (int msk = 1; msk < 16; msk <<= 1)
        #pragma unroll
        for (int st = 0; st < 2; ++st)
            #pragma unroll
            for (int r = 0; r < 4; ++r)
                lsum[st][r] += __shfl_xor(lsum[st][r], msk, 64);

    // direct normalize + store (wave owns its rows fully; no merge)
    #pragma unroll
    for (int st = 0; st < 2; ++st)
        #pragma unroll
        for (int r = 0; r < 4; ++r) {
            int qrow = w * 32 + st * 16 + g * 4 + r;
            float inv = 1.f / lsum[st][r];
            u16* op = Qbase + (size_t)(q0 + qrow) * 1024;
            #pragma unroll
            for (int nb = 0; nb < 4; ++nb)
                op[nb * 16 + l15] = f2bf(o[st][nb][r] * inv);
        }
}

// ---------------------------------------------------------------------------
extern "C" void kernel_launch(void* const* d_in, const int* in_sizes, int n_in,
                              void* d_out, int out_size, void* d_ws, size_t ws_size,
                              hipStream_t stream) {
    const float* x     = (const float*)d_in[0];
    const float* qkv_w = (const float*)d_in[1];
    const float* qkv_b = (const float*)d_in[2];
    const float* out_w = (const float*)d_in[3];
    const float* out_b = (const float*)d_in[4];
    float* out = (float*)d_out;

    const int M = BATCH * SEQ;                             // 8192
    u16* Qd     = (u16*)d_ws;                              // [M][1024]      16.8 MB
    u16* pkK    = Qd  + (size_t)M * D_MODEL;               // [64][32][4096] 16.8 MB
    u16* pkV    = pkK + (size_t)64 * 32 * 4096;            //                16.8 MB
    u16* xb     = pkV + (size_t)64 * 32 * 4096;            // [M][1024]      16.8 MB
    u16* Wqkv_t = xb  + (size_t)M * D_MODEL;               // [3072][1024]    6.3 MB
    u16* Wout_t = Wqkv_t + (size_t)3 * D_MODEL * D_MODEL;  // [1024][1024]    2.1 MB

    // merged prepass: cvt + both weight transposes in one launch
    prepass<<<dim3(8192), 256, 0, stream>>>(x, xb, qkv_w, Wqkv_t, out_w, Wout_t);

    // QKV projection with fused scatter into Qd / packed K / packed V
    gemm_qkv<<<dim3(M / 128, 3 * D_MODEL / 128), 256, 0, stream>>>(
        xb, Wqkv_t, qkv_b, Qd, pkK, pkV);

    // causal flash attention, 2-wave blocks, one q-tile each, LPT order
    attn_flash<<<dim3(BATCH * NH, SEQ / 64), 128, 0, stream>>>(Qd, pkK, pkV);

    // output projection
    gemm_bt<float><<<dim3(M / 128, D_MODEL / 128), 256, 0, stream>>>(
        Qd, D_MODEL, Wout_t, D_MODEL, out_b, out, D_MODEL, D_MODEL);
}